// Round 16
// baseline (27123.929 us; speedup 1.0000x reference)
//
#include <hip/hip_runtime.h>

typedef short short8 __attribute__((ext_vector_type(8)));
typedef float f32x4  __attribute__((ext_vector_type(4)));
typedef unsigned long long u64;

#define NWG 96           // 32 wgs per layer, 16 units each
#define NSTEP 515
#define NGRP 8           // barrier groups
#define GSZ  12          // arrivers per group (96/8)

// ---- workspace layout (bytes) ----
#define OFF_WH1  0ull              // packed Whh1 frags: 32 ug * 64KB = 2MB
#define OFF_WH2  2097152ull        // packed Whh2
#define OFF_WH3  4194304ull        // packed Whh3
#define OFF_WI2  6291456ull        // packed Wih2 (streamed, L2-resident)
#define OFF_WI3  8388608ull        // packed Wih3
#define OFF_V1   10485760ull       // v1[2048] f32 (Wih1 @ W1)
#define OFF_U1   10493952ull       // u1[2048] f32 (Wih1 @ b1 + bih1 + bhh1)
#define OFF_B2   10502144ull       // bias2[2048] f32
#define OFF_B3   10510336ull       // bias3[2048] f32
#define OFF_XT   10518528ull       // xT[512][128] f32 (256KB)
#define OFF_HR   10780672ull       // h rings: [3 layer][2 slot][16 kb][8 mb][512] u16 = 768KB
#define OFF_P3   11567104ull       // part3: [3 slot][32][128] f32 = 48KB (3-ring)
#define OFF_BAR  11616256ull       // barrier block (4KB): set0 @u32[0], set2 @[320], abl @[640]

__device__ __forceinline__ unsigned short bf16rne(float f) {
    unsigned u = __float_as_uint(f);
    return (unsigned short)((u + 0x7FFFu + ((u >> 16) & 1u)) >> 16);
}

__device__ __forceinline__ float sigm(float x) { return 1.0f / (1.0f + expf(-x)); }

// Coherent 16B load (sc0 sc1, bypasses stale L2); batched, then one vm_drain.
__device__ __forceinline__ short8 cload16(const void* p) {
    short8 r;
    asm volatile("global_load_dwordx4 %0, %1, off sc0 sc1" : "=v"(r) : "v"(p));
    return r;
}
__device__ __forceinline__ void vm_drain() {
    asm volatile("s_waitcnt vmcnt(0)" ::: "memory");
    __builtin_amdgcn_sched_barrier(0);
}

__global__ void fill_sentinel(float* __restrict__ out)
{
    int e = blockIdx.x * 256 + threadIdx.x;
    if (e < 65536) out[e] = 0.75f;
}

__global__ void zero_bar(char* __restrict__ ws)
{
    ((unsigned*)(ws + OFF_BAR))[threadIdx.x] = 0u;   // 1024 thr clear 4KB
}

__global__ void zero_hr(char* __restrict__ ws)
{
    int e = blockIdx.x * 256 + threadIdx.x;
    float4 z = {0.f, 0.f, 0.f, 0.f};
    if (e < 52224) *(float4*)(ws + OFF_HR + (size_t)e * 16) = z;  // HR(768K)+P3(48K)
}

__global__ void pack_w(const float* __restrict__ W, unsigned short* __restrict__ dst)
{
    int e = blockIdx.x * 256 + threadIdx.x;     // exactly 1,048,576
    int j    = e & 7;
    int lane = (e >> 3) & 63;
    int kb   = (e >> 9) & 15;
    int nb   = (e >> 13) & 3;
    int ug   = e >> 15;
    int row = nb * 512 + ug * 16 + (lane & 15);
    int col = kb * 32 + (lane >> 4) * 8 + j;
    dst[e] = bf16rne(W[row * 512 + col]);
}

__global__ void prep_vec(const float* __restrict__ Wih1, const float* __restrict__ W1,
                         const float* __restrict__ b1,
                         const float* __restrict__ bih1, const float* __restrict__ bhh1,
                         const float* __restrict__ bih2, const float* __restrict__ bhh2,
                         const float* __restrict__ bih3, const float* __restrict__ bhh3,
                         float* __restrict__ v1, float* __restrict__ u1,
                         float* __restrict__ bias2, float* __restrict__ bias3)
{
    int r = blockIdx.x * 256 + threadIdx.x;
    if (r >= 2048) return;
    float sv = 0.f, su = 0.f;
    for (int k = 0; k < 512; ++k) {
        float w = Wih1[r * 512 + k];
        sv += w * W1[k];
        su += w * b1[k];
    }
    v1[r] = sv;
    u1[r] = su + bih1[r] + bhh1[r];
    bias2[r] = bih2[r] + bhh2[r];
    bias3[r] = bih3[r] + bhh3[r];
}

__global__ void prep_xt(const float* __restrict__ x, float* __restrict__ xT)
{
    int e = blockIdx.x * 256 + threadIdx.x;
    if (e >= 65536) return;
    int b = e >> 9, t = e & 511;
    xT[t * 128 + b] = x[e];
}

// ---- fence-free hierarchical split-phase barrier ----
__device__ __forceinline__ void gbar_arrive(unsigned* bar, int wg, unsigned s)
{
    __syncthreads();
    if (threadIdx.x == 0) {
        unsigned g = (unsigned)wg & 7u;
        unsigned old = atomicAdd(bar + 64 + g * 32, 1u);
        if (old == s * GSZ - 1) {
            unsigned ro = atomicAdd(bar, 1u);
            if (ro == s * NGRP - 1)
                __hip_atomic_store(bar + 32, s, __ATOMIC_RELAXED,
                                   __HIP_MEMORY_SCOPE_AGENT);
        }
    }
}
__device__ __forceinline__ void gbar_wait(unsigned* bar, unsigned s)
{
    if (threadIdx.x == 0) {
        while (__hip_atomic_load(bar + 32, __ATOMIC_RELAXED,
                                 __HIP_MEMORY_SCOPE_AGENT) < s)
            __builtin_amdgcn_s_sleep(1);
    }
    __syncthreads();
}

// ---- ABLATION: pure barrier cost ----
__global__ void __launch_bounds__(256) abl_bar(char* __restrict__ ws, int iters, int ofs)
{
    unsigned* bar = (unsigned*)(ws + OFF_BAR) + ofs;
    unsigned s = 0;
    for (int i = 0; i < iters; ++i) {
        ++s;
        gbar_arrive(bar, blockIdx.x, s);
        gbar_wait(bar, s);
    }
}

// MODE 0: real (loads + barrier + out). MODE 1: no barrier. MODE 2: no h-loads.
template<int MODE>
__global__ void __launch_bounds__(256)
lstm_tpl(char* __restrict__ ws, const float* __restrict__ W2,
         const float* __restrict__ b2, float* __restrict__ out, int barofs)
{
    extern __shared__ char ldsraw[];
    unsigned short* w_lds = (unsigned short*)ldsraw;       // 32768 u16 = 64KB
    __shared__ __align__(16) unsigned short stage[4][2][16][16];

    const int tid  = threadIdx.x;
    const int lane = tid & 63;
    const int wv   = tid >> 6;
    const int q    = lane >> 4;
    const int l15  = lane & 15;
    const int wg   = blockIdx.x;
    const int layer = wg >> 5;
    const int ug    = wg & 31;

    unsigned short* hr = (unsigned short*)(ws + OFF_HR);
    float* part3 = (float*)(ws + OFF_P3);
    const float* xT = (const float*)(ws + OFF_XT);
    unsigned* bar = (unsigned*)(ws + OFF_BAR) + barofs;

    {
        const unsigned short* src = (const unsigned short*)
            (ws + ((layer == 0) ? OFF_WH1 : (layer == 1) ? OFF_WH2 : OFF_WH3))
            + (size_t)ug * 32768;
        for (int i = tid * 8; i < 32768; i += 256 * 8)
            *(short8*)(w_lds + i) = *(const short8*)(src + i);
    }
    float cv[4], cu_[4];
    {
        int gu = ug * 16 + l15;
        if (layer == 0) {
            const float* v1 = (const float*)(ws + OFF_V1);
            const float* u1 = (const float*)(ws + OFF_U1);
            #pragma unroll
            for (int g = 0; g < 4; ++g) { cv[g] = v1[g * 512 + gu]; cu_[g] = u1[g * 512 + gu]; }
        } else {
            const float* bs = (const float*)(ws + ((layer == 1) ? OFF_B2 : OFF_B3));
            #pragma unroll
            for (int g = 0; g < 4; ++g) { cv[g] = bs[g * 512 + gu]; cu_[g] = 0.f; }
        }
    }
    const float w2v = (layer == 2) ? W2[ug * 16 + l15] : 0.f;
    const float b2v = b2[0];
    const unsigned short* wi_g = (const unsigned short*)
        (ws + ((layer == 1) ? OFF_WI2 : OFF_WI3)) + (size_t)ug * 32768;

    float c_st[2][4] = {};
    __syncthreads();                // w_lds parked

    short8 A[32];
    if constexpr (MODE == 2) {      // load A once; reuse every step
        const unsigned short* hS = hr + (size_t)(layer * 2) * 65536;
        #pragma unroll
        for (int kb = 0; kb < 16; ++kb) {
            A[2 * kb]     = cload16(hS + (kb * 8 + 2 * wv    ) * 512 + lane * 8);
            A[2 * kb + 1] = cload16(hS + (kb * 8 + 2 * wv + 1) * 512 + lane * 8);
        }
        vm_drain();
    }

    unsigned bstep = 0;
    for (int w = 0; w < NSTEP; ++w) {
        const int cur = w & 1, prev = cur ^ 1;
        const int t = w - layer;
        if (t >= 0 && t < 512) {
            f32x4 acc[2][4] = {};
            // mat 0 (layers 1,2)
            if (layer != 0) {
                if constexpr (MODE != 2) {
                    const unsigned short* hA = hr + (size_t)((layer - 1) * 2 + prev) * 65536;
                    #pragma unroll
                    for (int kb = 0; kb < 16; ++kb) {
                        A[2 * kb]     = cload16(hA + (kb * 8 + 2 * wv    ) * 512 + lane * 8);
                        A[2 * kb + 1] = cload16(hA + (kb * 8 + 2 * wv + 1) * 512 + lane * 8);
                    }
                    vm_drain();
                }
                #pragma unroll
                for (int kb = 0; kb < 16; ++kb) {
                    #pragma unroll
                    for (int nb = 0; nb < 4; ++nb) {
                        short8 bw = *(const short8*)(wi_g + ((nb * 16 + kb) * 512) + lane * 8);
                        acc[0][nb] = __builtin_amdgcn_mfma_f32_16x16x32_bf16(A[2 * kb],     bw, acc[0][nb], 0, 0, 0);
                        acc[1][nb] = __builtin_amdgcn_mfma_f32_16x16x32_bf16(A[2 * kb + 1], bw, acc[1][nb], 0, 0, 0);
                    }
                }
            }
            // mat 1
            {
                if constexpr (MODE != 2) {
                    const unsigned short* hS = hr + (size_t)(layer * 2 + prev) * 65536;
                    #pragma unroll
                    for (int kb = 0; kb < 16; ++kb) {
                        A[2 * kb]     = cload16(hS + (kb * 8 + 2 * wv    ) * 512 + lane * 8);
                        A[2 * kb + 1] = cload16(hS + (kb * 8 + 2 * wv + 1) * 512 + lane * 8);
                    }
                    vm_drain();
                }
                #pragma unroll
                for (int kb = 0; kb < 16; ++kb) {
                    #pragma unroll
                    for (int nb = 0; nb < 4; ++nb) {
                        short8 bw = *(const short8*)(w_lds + ((nb * 16 + kb) * 512) + lane * 8);
                        acc[0][nb] = __builtin_amdgcn_mfma_f32_16x16x32_bf16(A[2 * kb],     bw, acc[0][nb], 0, 0, 0);
                        acc[1][nb] = __builtin_amdgcn_mfma_f32_16x16x32_bf16(A[2 * kb + 1], bw, acc[1][nb], 0, 0, 0);
                    }
                }
            }
            // epilogue
            #pragma unroll
            for (int m = 0; m < 2; ++m) {
                const int mblk = 2 * wv + m;
                #pragma unroll
                for (int rr = 0; rr < 4; ++rr) {
                    const int b = mblk * 16 + q * 4 + rr;
                    const float xv = (layer == 0) ? xT[t * 128 + b] : 1.0f;
                    float gi = acc[m][0][rr] + xv * cv[0] + cu_[0];
                    float gf = acc[m][1][rr] + xv * cv[1] + cu_[1];
                    float gg = acc[m][2][rr] + xv * cv[2] + cu_[2];
                    float go = acc[m][3][rr] + xv * cv[3] + cu_[3];
                    float c = sigm(gf) * c_st[m][rr] + sigm(gi) * tanhf(gg);
                    c_st[m][rr] = c;
                    float h = sigm(go) * tanhf(c);
                    stage[wv][m][q * 4 + rr][l15] = bf16rne(h);
                    if (layer == 2) {
                        float v = h * w2v;
                        v += __shfl_xor(v, 1); v += __shfl_xor(v, 2);
                        v += __shfl_xor(v, 4); v += __shfl_xor(v, 8);
                        if (l15 == 0)
                            __hip_atomic_store(&part3[((size_t)(w % 3) * 32 + ug) * 128 + b],
                                               v, __ATOMIC_RELAXED, __HIP_MEMORY_SCOPE_AGENT);
                    }
                }
            }
            // publish h
            #pragma unroll
            for (int m = 0; m < 2; ++m) {
                const int mblk = 2 * wv + m;
                u64* dst64 = (u64*)(hr + (size_t)(layer * 2 + cur) * 65536
                                       + ((size_t)(ug >> 1) * 8 + mblk) * 512);
                const int row = lane >> 2, q4 = lane & 3;
                u64 v = *(const u64*)&stage[wv][m][row][q4 * 4];
                const int idx = (((ug & 1) * 2 + (q4 >> 1)) * 16 + row) * 2 + (q4 & 1);
                __hip_atomic_store(dst64 + idx, v, __ATOMIC_RELAXED,
                                   __HIP_MEMORY_SCOPE_AGENT);
            }
        }
        if constexpr (MODE == 1) {
            __syncthreads();                       // intra-wg sync only
        } else {
            gbar_arrive(bar, wg, ++bstep);
            if constexpr (MODE == 0) {
                if (layer == 2 && w >= 3) {
                    const int b = (wg - 64) * 4 + wv;
                    float v = 0.f;
                    if (lane < 32)
                        v = __hip_atomic_load(&part3[((size_t)((w - 1) % 3) * 32 + lane) * 128 + b],
                                              __ATOMIC_RELAXED, __HIP_MEMORY_SCOPE_AGENT);
                    v += __shfl_xor(v, 1); v += __shfl_xor(v, 2); v += __shfl_xor(v, 4);
                    v += __shfl_xor(v, 8); v += __shfl_xor(v, 16);
                    if (lane == 0) out[(size_t)b * 512 + (w - 3)] = v + b2v;
                }
            }
            gbar_wait(bar, bstep);
        }
    }
}

// Kept to match the harness-provided template symbol (unused).
__global__ void Sequence_85564338471528_kernel() {}

extern "C" void kernel_launch(void* const* d_in, const int* in_sizes, int n_in,
                              void* d_out, int out_size, void* d_ws, size_t ws_size,
                              hipStream_t stream)
{
    const float* x    = (const float*)d_in[0];
    const float* W1   = (const float*)d_in[2];
    const float* b1   = (const float*)d_in[3];
    const float* W2   = (const float*)d_in[4];
    const float* b2   = (const float*)d_in[5];
    const float* Wih1 = (const float*)d_in[6];
    const float* Whh1 = (const float*)d_in[7];
    const float* bih1 = (const float*)d_in[8];
    const float* bhh1 = (const float*)d_in[9];
    const float* Wih2 = (const float*)d_in[10];
    const float* Whh2 = (const float*)d_in[11];
    const float* bih2 = (const float*)d_in[12];
    const float* bhh2 = (const float*)d_in[13];
    const float* Wih3 = (const float*)d_in[14];
    const float* Whh3 = (const float*)d_in[15];
    const float* bih3 = (const float*)d_in[16];
    const float* bhh3 = (const float*)d_in[17];
    char* ws = (char*)d_ws;
    float* out = (float*)d_out;

    fill_sentinel<<<256, 256, 0, stream>>>(out);
    zero_bar<<<1, 1024, 0, stream>>>(ws);
    zero_hr<<<204, 256, 0, stream>>>(ws);

    pack_w<<<4096, 256, 0, stream>>>(Whh1, (unsigned short*)(ws + OFF_WH1));
    pack_w<<<4096, 256, 0, stream>>>(Whh2, (unsigned short*)(ws + OFF_WH2));
    pack_w<<<4096, 256, 0, stream>>>(Whh3, (unsigned short*)(ws + OFF_WH3));
    pack_w<<<4096, 256, 0, stream>>>(Wih2, (unsigned short*)(ws + OFF_WI2));
    pack_w<<<4096, 256, 0, stream>>>(Wih3, (unsigned short*)(ws + OFF_WI3));
    prep_vec<<<8, 256, 0, stream>>>(Wih1, W1, b1, bih1, bhh1, bih2, bhh2, bih3, bhh3,
                                    (float*)(ws + OFF_V1), (float*)(ws + OFF_U1),
                                    (float*)(ws + OFF_B2), (float*)(ws + OFF_B3));
    prep_xt<<<256, 256, 0, stream>>>(x, (float*)(ws + OFF_XT));

    // REAL run (validates): barrier set 0
    lstm_tpl<0><<<dim3(NWG), dim3(256), 65536, stream>>>(ws, W2, b2, out, 0);
    // ABLATION A: no global barrier (free-running compute chain)
    lstm_tpl<1><<<dim3(NWG), dim3(256), 65536, stream>>>(ws, W2, b2, out, 0);
    // ABLATION B: no coherent h-loads (barrier set 2 @ u32 ofs 320)
    lstm_tpl<2><<<dim3(NWG), dim3(256), 65536, stream>>>(ws, W2, b2, out, 320);
    // ABLATION C: barrier only, 515 iters (set 3 @ u32 ofs 640)
    abl_bar<<<dim3(NWG), dim3(256), 0, stream>>>(ws, NSTEP, 640);
}

// Round 17
// 7449.490 us; speedup vs baseline: 3.6410x; 3.6410x over previous
//
#include <hip/hip_runtime.h>

typedef short short8 __attribute__((ext_vector_type(8)));
typedef float f32x4  __attribute__((ext_vector_type(4)));
typedef unsigned long long u64;

#define NSTEP 515

// ---- workspace layout (bytes) ----
#define OFF_WH1  0ull              // packed Whh1 frags (kb-major): 32 ug * 64KB = 2MB
#define OFF_WH2  2097152ull        // packed Whh2
#define OFF_WH3  4194304ull        // packed Whh3
#define OFF_WI2  6291456ull        // packed Wih2
#define OFF_WI3  8388608ull        // packed Wih3
#define OFF_V1   10485760ull       // v1[2048] f32 (Wih1 @ W1)
#define OFF_U1   10493952ull       // u1[2048] f32 (Wih1 @ b1 + bih1 + bhh1)
#define OFF_B2   10502144ull       // bias2[2048] f32
#define OFF_B3   10510336ull       // bias3[2048] f32
#define OFF_XT   10518528ull       // xT[512][128] f32 (256KB)
#define OFF_HR   10780672ull       // h rings: [3 layer][2 slot][16 kb][8 mb][512] u16 = 768KB
#define OFF_P3   11567104ull       // part3: [3 slot][32][128] f32 = 48KB (3-ring)
#define OFF_C    11616256ull       // cell state: [3][128][512] f32 = 768KB

__device__ __forceinline__ unsigned short bf16rne(float f) {
    unsigned u = __float_as_uint(f);
    return (unsigned short)((u + 0x7FFFu + ((u >> 16) & 1u)) >> 16);
}

__device__ __forceinline__ float sigm(float x) { return 1.0f / (1.0f + expf(-x)); }

// Sentinel: 0.0508 absmax -> nothing ran; ~0.75 -> step_k broken; ~2e-4 -> PASS.
__global__ void fill_sentinel(float* __restrict__ out)
{
    int e = blockIdx.x * 256 + threadIdx.x;
    if (e < 65536) out[e] = 0.75f;
}

// Zero h rings + part3 + cell state (contiguous 1584KB) in a PRE-kernel.
__global__ void zero_state(char* __restrict__ ws)
{
    int e = blockIdx.x * 256 + threadIdx.x;
    float4 z = {0.f, 0.f, 0.f, 0.f};
    if (e < 101376) *(float4*)(ws + OFF_HR + (size_t)e * 16) = z;
}

// Pack one 2048x512 gate matrix into MFMA B-fragments, KB-MAJOR order:
// e = ((((ug*16 + kb)*4 + nb)*64 + lane)*8 + j
// value = W[nb*512 + ug*16 + (lane&15)][kb*32 + (lane>>4)*8 + j]
__global__ void pack_w(const float* __restrict__ W, unsigned short* __restrict__ dst)
{
    int e = blockIdx.x * 256 + threadIdx.x;     // exactly 1,048,576
    int j    = e & 7;
    int lane = (e >> 3) & 63;
    int nb   = (e >> 9) & 3;
    int kb   = (e >> 11) & 15;
    int ug   = e >> 15;
    int row = nb * 512 + ug * 16 + (lane & 15);
    int col = kb * 32 + (lane >> 4) * 8 + j;
    dst[e] = bf16rne(W[row * 512 + col]);
}

// v1 = Wih1 @ W1[:,0]; u1 = Wih1 @ b1 + bih1 + bhh1; bias2/3 = bih+bhh
__global__ void prep_vec(const float* __restrict__ Wih1, const float* __restrict__ W1,
                         const float* __restrict__ b1,
                         const float* __restrict__ bih1, const float* __restrict__ bhh1,
                         const float* __restrict__ bih2, const float* __restrict__ bhh2,
                         const float* __restrict__ bih3, const float* __restrict__ bhh3,
                         float* __restrict__ v1, float* __restrict__ u1,
                         float* __restrict__ bias2, float* __restrict__ bias3)
{
    int r = blockIdx.x * 256 + threadIdx.x;
    if (r >= 2048) return;
    float sv = 0.f, su = 0.f;
    for (int k = 0; k < 512; ++k) {
        float w = Wih1[r * 512 + k];
        sv += w * W1[k];
        su += w * b1[k];
    }
    v1[r] = sv;
    u1[r] = su + bih1[r] + bhh1[r];
    bias2[r] = bih2[r] + bhh2[r];
    bias3[r] = bih3[r] + bhh3[r];
}

__global__ void prep_xt(const float* __restrict__ x, float* __restrict__ xT)
{
    int e = blockIdx.x * 256 + threadIdx.x;
    if (e >= 65536) return;
    int b = e >> 9, t = e & 511;
    xT[t * 128 + b] = x[e];
}

// One skewed step. Kernel boundary = global sync (implicit coherence).
// wg 0..95: layer = wg>>5, ug = wg&31 (16 units, all 128 batches, 4 waves).
// wg 96: out-projection reduce for t_o = w-3 from part3 slot (w-1)%3.
// B-frags staged to LDS in 32KB halves (kb-major pack makes halves contiguous).
__global__ void __launch_bounds__(256)
step_k(char* __restrict__ ws, const float* __restrict__ W2,
       const float* __restrict__ b2, float* __restrict__ out, int w)
{
    __shared__ __align__(16) unsigned short bsh[16384];           // 32KB B half-mat
    __shared__ __align__(16) unsigned short stage[4][2][16][16];  // 4KB transpose

    const int cur = w & 1, prev = cur ^ 1;
    const int tid = threadIdx.x, lane = tid & 63, wv = tid >> 6;
    const int q = lane >> 4, l15 = lane & 15;
    const int wg = blockIdx.x;

    unsigned short* hr = (unsigned short*)(ws + OFF_HR);
    float* part3 = (float*)(ws + OFF_P3);

    if (wg == 96) {                                 // out[b][w-3]
        if (w < 3 || tid >= 128) return;
        const int b = tid;
        const float* p = part3 + (size_t)((w - 1) % 3) * 32 * 128;
        float v = 0.f;
        #pragma unroll
        for (int i = 0; i < 32; ++i) v += p[i * 128 + b];
        out[(size_t)b * 512 + (w - 3)] = v + b2[0];
        return;
    }

    const int layer = wg >> 5, ug = wg & 31;
    const int t = w - layer;
    if (t < 0 || t >= 512) return;
    const int nmats = (layer == 0) ? 1 : 2;
    const int gu = ug * 16 + l15;

    // per-lane constants (L2-hot)
    float cv[4], cu_[4];
    if (layer == 0) {
        const float* v1 = (const float*)(ws + OFF_V1);
        const float* u1 = (const float*)(ws + OFF_U1);
        #pragma unroll
        for (int g = 0; g < 4; ++g) { cv[g] = v1[g * 512 + gu]; cu_[g] = u1[g * 512 + gu]; }
    } else {
        const float* bs = (const float*)(ws + ((layer == 1) ? OFF_B2 : OFF_B3));
        #pragma unroll
        for (int g = 0; g < 4; ++g) { cv[g] = bs[g * 512 + gu]; cu_[g] = 0.f; }
    }
    const float w2v = (layer == 2) ? W2[gu] : 0.f;
    const float* xT = (const float*)(ws + OFF_XT);
    float* C = (float*)(ws + OFF_C);

    // cell state from global
    float c_st[2][4];
    #pragma unroll
    for (int m = 0; m < 2; ++m)
        #pragma unroll
        for (int rr = 0; rr < 4; ++rr) {
            const int b = (2 * wv + m) * 16 + q * 4 + rr;
            c_st[m][rr] = C[((size_t)layer * 128 + b) * 512 + gu];
        }

    f32x4 acc[2][4] = {};
    for (int mat = 0; mat < nmats; ++mat) {
        const int srcL = (layer == 0) ? 0 : ((mat == 0) ? layer - 1 : layer);
        const unsigned short* hsrc = hr + (size_t)(srcL * 2 + prev) * 65536;
        const unsigned short* wsrc;
        if (layer == 0)
            wsrc = (const unsigned short*)(ws + OFF_WH1) + (size_t)ug * 32768;
        else if (mat == 0)
            wsrc = (const unsigned short*)(ws + ((layer == 1) ? OFF_WI2 : OFF_WI3)) + (size_t)ug * 32768;
        else
            wsrc = (const unsigned short*)(ws + ((layer == 1) ? OFF_WH2 : OFF_WH3)) + (size_t)ug * 32768;

        for (int hh = 0; hh < 2; ++hh) {
            __syncthreads();                        // prior consume of bsh done
            // stage 32KB of B (kb in [hh*8, hh*8+8)), contiguous
            for (int i = tid * 8; i < 16384; i += 256 * 8)
                *(short8*)(bsh + i) = *(const short8*)(wsrc + hh * 16384 + i);
            // A-frags for this half (global, independent of LDS)
            short8 A16[16];
            #pragma unroll
            for (int kb2 = 0; kb2 < 8; ++kb2) {
                const int kbg = hh * 8 + kb2;
                A16[2 * kb2]     = *(const short8*)(hsrc + ((kbg * 8 + 2 * wv    ) * 512) + lane * 8);
                A16[2 * kb2 + 1] = *(const short8*)(hsrc + ((kbg * 8 + 2 * wv + 1) * 512) + lane * 8);
            }
            __syncthreads();                        // staging visible
            #pragma unroll
            for (int kb2 = 0; kb2 < 8; ++kb2) {
                #pragma unroll
                for (int nb = 0; nb < 4; ++nb) {
                    short8 bw = *(const short8*)(bsh + (kb2 * 4 + nb) * 512 + lane * 8);
                    acc[0][nb] = __builtin_amdgcn_mfma_f32_16x16x32_bf16(A16[2 * kb2],     bw, acc[0][nb], 0, 0, 0);
                    acc[1][nb] = __builtin_amdgcn_mfma_f32_16x16x32_bf16(A16[2 * kb2 + 1], bw, acc[1][nb], 0, 0, 0);
                }
            }
        }
    }

    // epilogue: gates in-lane (unit gu), batch b = mblk*16 + q*4 + rr
    #pragma unroll
    for (int m = 0; m < 2; ++m) {
        const int mblk = 2 * wv + m;
        #pragma unroll
        for (int rr = 0; rr < 4; ++rr) {
            const int b = mblk * 16 + q * 4 + rr;
            const float xv = (layer == 0) ? xT[t * 128 + b] : 1.0f;
            float gi = acc[m][0][rr] + xv * cv[0] + cu_[0];
            float gf = acc[m][1][rr] + xv * cv[1] + cu_[1];
            float gg = acc[m][2][rr] + xv * cv[2] + cu_[2];
            float go = acc[m][3][rr] + xv * cv[3] + cu_[3];
            float c = sigm(gf) * c_st[m][rr] + sigm(gi) * tanhf(gg);
            C[((size_t)layer * 128 + b) * 512 + gu] = c;
            float h = sigm(go) * tanhf(c);
            stage[wv][m][q * 4 + rr][l15] = bf16rne(h);
            if (layer == 2) {
                float v = h * w2v;                  // partial of out[b][t]
                v += __shfl_xor(v, 1); v += __shfl_xor(v, 2);
                v += __shfl_xor(v, 4); v += __shfl_xor(v, 8);
                if (l15 == 0)
                    part3[((size_t)(w % 3) * 32 + ug) * 128 + b] = v;
            }
        }
    }
    // publish h fragment (plain stores; next dispatch sees them)
    #pragma unroll
    for (int m = 0; m < 2; ++m) {
        const int mblk = 2 * wv + m;
        u64* dst64 = (u64*)(hr + (size_t)(layer * 2 + cur) * 65536
                               + ((size_t)(ug >> 1) * 8 + mblk) * 512);
        const int row = lane >> 2, q4 = lane & 3;
        u64 v = *(const u64*)&stage[wv][m][row][q4 * 4];
        const int idx = (((ug & 1) * 2 + (q4 >> 1)) * 16 + row) * 2 + (q4 & 1);
        dst64[idx] = v;
    }
}

// Kept to match the harness-provided template symbol (unused).
__global__ void Sequence_85564338471528_kernel() {}

extern "C" void kernel_launch(void* const* d_in, const int* in_sizes, int n_in,
                              void* d_out, int out_size, void* d_ws, size_t ws_size,
                              hipStream_t stream)
{
    const float* x    = (const float*)d_in[0];
    const float* W1   = (const float*)d_in[2];
    const float* b1   = (const float*)d_in[3];
    const float* W2   = (const float*)d_in[4];
    const float* b2   = (const float*)d_in[5];
    const float* Wih1 = (const float*)d_in[6];
    const float* Whh1 = (const float*)d_in[7];
    const float* bih1 = (const float*)d_in[8];
    const float* bhh1 = (const float*)d_in[9];
    const float* Wih2 = (const float*)d_in[10];
    const float* Whh2 = (const float*)d_in[11];
    const float* bih2 = (const float*)d_in[12];
    const float* bhh2 = (const float*)d_in[13];
    const float* Wih3 = (const float*)d_in[14];
    const float* Whh3 = (const float*)d_in[15];
    const float* bih3 = (const float*)d_in[16];
    const float* bhh3 = (const float*)d_in[17];
    char* ws = (char*)d_ws;
    float* out = (float*)d_out;

    fill_sentinel<<<256, 256, 0, stream>>>(out);
    zero_state<<<396, 256, 0, stream>>>(ws);

    pack_w<<<4096, 256, 0, stream>>>(Whh1, (unsigned short*)(ws + OFF_WH1));
    pack_w<<<4096, 256, 0, stream>>>(Whh2, (unsigned short*)(ws + OFF_WH2));
    pack_w<<<4096, 256, 0, stream>>>(Whh3, (unsigned short*)(ws + OFF_WH3));
    pack_w<<<4096, 256, 0, stream>>>(Wih2, (unsigned short*)(ws + OFF_WI2));
    pack_w<<<4096, 256, 0, stream>>>(Wih3, (unsigned short*)(ws + OFF_WI3));
    prep_vec<<<8, 256, 0, stream>>>(Wih1, W1, b1, bih1, bhh1, bih2, bhh2, bih3, bhh3,
                                    (float*)(ws + OFF_V1), (float*)(ws + OFF_U1),
                                    (float*)(ws + OFF_B2), (float*)(ws + OFF_B3));
    prep_xt<<<256, 256, 0, stream>>>(x, (float*)(ws + OFF_XT));

    for (int w = 0; w < NSTEP; ++w)
        step_k<<<97, 256, 0, stream>>>(ws, W2, b2, out, w);
}

// Round 18
// 5872.548 us; speedup vs baseline: 4.6188x; 1.2685x over previous
//
#include <hip/hip_runtime.h>

typedef short short8 __attribute__((ext_vector_type(8)));
typedef float f32x4  __attribute__((ext_vector_type(4)));
typedef unsigned long long u64;

#define NSTEP 515

// ---- workspace layout (bytes) ----
#define OFF_WH1  0ull              // packed Whh1 frags (kb-major): 32 ug * 64KB = 2MB
#define OFF_WH2  2097152ull        // packed Whh2
#define OFF_WH3  4194304ull        // packed Whh3
#define OFF_WI2  6291456ull        // packed Wih2
#define OFF_WI3  8388608ull        // packed Wih3
#define OFF_V1   10485760ull       // v1[2048] f32 (Wih1 @ W1)
#define OFF_U1   10493952ull       // u1[2048] f32 (Wih1 @ b1 + bih1 + bhh1)
#define OFF_B2   10502144ull       // bias2[2048] f32
#define OFF_B3   10510336ull       // bias3[2048] f32
#define OFF_XT   10518528ull       // xT[512][128] f32 (256KB)
#define OFF_HR   10780672ull       // h rings: [3 layer][2 slot][16 kb][8 mb][512] u16 = 768KB
#define OFF_P3   11567104ull       // part3: [3 slot][32][128] f32 = 48KB (3-ring)
#define OFF_C    11616256ull       // cell state: [3][128][512] f32 = 768KB

__device__ __forceinline__ unsigned short bf16rne(float f) {
    unsigned u = __float_as_uint(f);
    return (unsigned short)((u + 0x7FFFu + ((u >> 16) & 1u)) >> 16);
}

__device__ __forceinline__ float sigm(float x) { return 1.0f / (1.0f + expf(-x)); }

// Sentinel: 0.0508 absmax -> nothing ran; ~0.75 -> step_k broken; ~2e-4 -> PASS.
__global__ void fill_sentinel(float* __restrict__ out)
{
    int e = blockIdx.x * 256 + threadIdx.x;
    if (e < 65536) out[e] = 0.75f;
}

// Zero h rings + part3 + cell state (contiguous 1584KB).
__global__ void zero_state(char* __restrict__ ws)
{
    int e = blockIdx.x * 256 + threadIdx.x;
    float4 z = {0.f, 0.f, 0.f, 0.f};
    if (e < 101376) *(float4*)(ws + OFF_HR + (size_t)e * 16) = z;
}

// Pack one 2048x512 gate matrix into MFMA B-fragments, KB-MAJOR:
// e = (((ug*16 + kb)*4 + nb)*64 + lane)*8 + j
// value = W[nb*512 + ug*16 + (lane&15)][kb*32 + (lane>>4)*8 + j]
__global__ void pack_w(const float* __restrict__ W, unsigned short* __restrict__ dst)
{
    int e = blockIdx.x * 256 + threadIdx.x;     // exactly 1,048,576
    int j    = e & 7;
    int lane = (e >> 3) & 63;
    int nb   = (e >> 9) & 3;
    int kb   = (e >> 11) & 15;
    int ug   = e >> 15;
    int row = nb * 512 + ug * 16 + (lane & 15);
    int col = kb * 32 + (lane >> 4) * 8 + j;
    dst[e] = bf16rne(W[row * 512 + col]);
}

// v1 = Wih1 @ W1[:,0]; u1 = Wih1 @ b1 + bih1 + bhh1; bias2/3 = bih+bhh
__global__ void prep_vec(const float* __restrict__ Wih1, const float* __restrict__ W1,
                         const float* __restrict__ b1,
                         const float* __restrict__ bih1, const float* __restrict__ bhh1,
                         const float* __restrict__ bih2, const float* __restrict__ bhh2,
                         const float* __restrict__ bih3, const float* __restrict__ bhh3,
                         float* __restrict__ v1, float* __restrict__ u1,
                         float* __restrict__ bias2, float* __restrict__ bias3)
{
    int r = blockIdx.x * 256 + threadIdx.x;
    if (r >= 2048) return;
    float sv = 0.f, su = 0.f;
    for (int k = 0; k < 512; ++k) {
        float w = Wih1[r * 512 + k];
        sv += w * W1[k];
        su += w * b1[k];
    }
    v1[r] = sv;
    u1[r] = su + bih1[r] + bhh1[r];
    bias2[r] = bih2[r] + bhh2[r];
    bias3[r] = bih3[r] + bhh3[r];
}

__global__ void prep_xt(const float* __restrict__ x, float* __restrict__ xT)
{
    int e = blockIdx.x * 256 + threadIdx.x;
    if (e >= 65536) return;
    int b = e >> 9, t = e & 511;
    xT[t * 128 + b] = x[e];
}

// Double-buffered B-chunk GEMM. NM mats x 4 chunks of 16KB each.
// Chunk layout (kb-major pack): chunk c = kb in [c*4, c*4+4), 8192 shorts.
// Load chunk cc+1 into regs while MFMA consumes chunk cc from LDS.
template<int NM>
__device__ __forceinline__ void gemm_chunks(
    const unsigned short* __restrict__ wsrc0,
    const unsigned short* __restrict__ wsrc1,
    const short8 (&A)[NM][16],
    unsigned short (&bsh)[2][8192],
    int tid, int lane, f32x4 (&acc)[4])
{
    const unsigned short* wsrc[2] = { wsrc0, wsrc1 };
    short8 r0, r1;
    r0 = *(const short8*)(wsrc[0] + tid * 8);
    r1 = *(const short8*)(wsrc[0] + 4096 + tid * 8);
    *(short8*)(&bsh[0][tid * 8]) = r0;
    *(short8*)(&bsh[0][4096 + tid * 8]) = r1;
    __syncthreads();
    #pragma unroll
    for (int cc = 0; cc < 4 * NM; ++cc) {
        const int m = cc >> 2, c = cc & 3;
        const int nm_ = cc + 1;
        if (nm_ < 4 * NM) {
            const unsigned short* src = wsrc[nm_ >> 2] + (nm_ & 3) * 8192;
            r0 = *(const short8*)(src + tid * 8);
            r1 = *(const short8*)(src + 4096 + tid * 8);
        }
        (void)c;
        #pragma unroll
        for (int k2 = 0; k2 < 4; ++k2) {
            const int kb = (cc & 3) * 4 + k2;
            #pragma unroll
            for (int nb = 0; nb < 4; ++nb) {
                short8 bw = *(const short8*)(&bsh[cc & 1][(k2 * 4 + nb) * 512 + lane * 8]);
                acc[nb] = __builtin_amdgcn_mfma_f32_16x16x32_bf16(A[m][kb], bw, acc[nb], 0, 0, 0);
            }
        }
        if (nm_ < 4 * NM) {
            *(short8*)(&bsh[nm_ & 1][tid * 8]) = r0;
            *(short8*)(&bsh[nm_ & 1][4096 + tid * 8]) = r1;
        }
        __syncthreads();
    }
}

// One skewed step; kernel boundary = global sync.
// wg 0..95: layer = wg>>5, ug = wg&31; 512 thr = 8 waves, wave wv owns mblk=wv.
// wg 96: out-projection reduce for t_o = w-3.
__global__ void __launch_bounds__(512)
step_k(char* __restrict__ ws, const float* __restrict__ W2,
       const float* __restrict__ b2, float* __restrict__ out, int w)
{
    __shared__ __align__(16) unsigned short bsh[2][8192];        // 2 x 16KB dbuf
    __shared__ __align__(16) unsigned short stage[8][16][16];    // 4KB transpose

    const int cur = w & 1, prev = cur ^ 1;
    const int tid = threadIdx.x, lane = tid & 63, wv = tid >> 6;
    const int q = lane >> 4, l15 = lane & 15;
    const int wg = blockIdx.x;

    unsigned short* hr = (unsigned short*)(ws + OFF_HR);
    float* part3 = (float*)(ws + OFF_P3);

    if (wg == 96) {                                 // out[b][w-3]
        if (w < 3 || tid >= 128) return;
        const int b = tid;
        const float* p = part3 + (size_t)((w - 1) % 3) * 32 * 128;
        float v = 0.f;
        #pragma unroll
        for (int i = 0; i < 32; ++i) v += p[i * 128 + b];
        out[(size_t)b * 512 + (w - 3)] = v + b2[0];
        return;
    }

    const int layer = wg >> 5, ug = wg & 31;
    const int t = w - layer;
    if (t < 0 || t >= 512) return;
    const int gu = ug * 16 + l15;

    float cv[4], cu_[4];
    if (layer == 0) {
        const float* v1 = (const float*)(ws + OFF_V1);
        const float* u1 = (const float*)(ws + OFF_U1);
        #pragma unroll
        for (int g = 0; g < 4; ++g) { cv[g] = v1[g * 512 + gu]; cu_[g] = u1[g * 512 + gu]; }
    } else {
        const float* bs = (const float*)(ws + ((layer == 1) ? OFF_B2 : OFF_B3));
        #pragma unroll
        for (int g = 0; g < 4; ++g) { cv[g] = bs[g * 512 + gu]; cu_[g] = 0.f; }
    }
    const float w2v = (layer == 2) ? W2[gu] : 0.f;
    const float* xT = (const float*)(ws + OFF_XT);
    float* C = (float*)(ws + OFF_C);

    float c_st[4];
    #pragma unroll
    for (int rr = 0; rr < 4; ++rr) {
        const int b = wv * 16 + q * 4 + rr;
        c_st[rr] = C[((size_t)layer * 128 + b) * 512 + gu];
    }

    f32x4 acc[4] = {};
    if (layer == 0) {
        const unsigned short* hS = hr + (size_t)(0 * 2 + prev) * 65536;
        short8 A[1][16];
        #pragma unroll
        for (int kb = 0; kb < 16; ++kb)
            A[0][kb] = *(const short8*)(hS + ((kb * 8 + wv) * 512) + lane * 8);
        gemm_chunks<1>((const unsigned short*)(ws + OFF_WH1) + (size_t)ug * 32768,
                       nullptr, A, bsh, tid, lane, acc);
    } else {
        const unsigned short* hA0 = hr + (size_t)((layer - 1) * 2 + prev) * 65536;
        const unsigned short* hA1 = hr + (size_t)(layer * 2 + prev) * 65536;
        short8 A[2][16];
        #pragma unroll
        for (int kb = 0; kb < 16; ++kb)
            A[0][kb] = *(const short8*)(hA0 + ((kb * 8 + wv) * 512) + lane * 8);
        #pragma unroll
        for (int kb = 0; kb < 16; ++kb)
            A[1][kb] = *(const short8*)(hA1 + ((kb * 8 + wv) * 512) + lane * 8);
        gemm_chunks<2>((const unsigned short*)(ws + ((layer == 1) ? OFF_WI2 : OFF_WI3)) + (size_t)ug * 32768,
                       (const unsigned short*)(ws + ((layer == 1) ? OFF_WH2 : OFF_WH3)) + (size_t)ug * 32768,
                       A, bsh, tid, lane, acc);
    }

    // epilogue: gates in-lane (unit gu), batch b = wv*16 + q*4 + rr
    #pragma unroll
    for (int rr = 0; rr < 4; ++rr) {
        const int b = wv * 16 + q * 4 + rr;
        const float xv = (layer == 0) ? xT[t * 128 + b] : 1.0f;
        float gi = acc[0][rr] + xv * cv[0] + cu_[0];
        float gf = acc[1][rr] + xv * cv[1] + cu_[1];
        float gg = acc[2][rr] + xv * cv[2] + cu_[2];
        float go = acc[3][rr] + xv * cv[3] + cu_[3];
        float c = sigm(gf) * c_st[rr] + sigm(gi) * tanhf(gg);
        C[((size_t)layer * 128 + b) * 512 + gu] = c;
        float h = sigm(go) * tanhf(c);
        stage[wv][q * 4 + rr][l15] = bf16rne(h);
        if (layer == 2) {
            float v = h * w2v;                      // partial of out[b][t]
            v += __shfl_xor(v, 1); v += __shfl_xor(v, 2);
            v += __shfl_xor(v, 4); v += __shfl_xor(v, 8);
            if (l15 == 0)
                part3[((size_t)(w % 3) * 32 + ug) * 128 + b] = v;
        }
    }
    // publish h fragment (plain stores; next dispatch sees them)
    {
        u64* dst64 = (u64*)(hr + (size_t)(layer * 2 + cur) * 65536
                               + ((size_t)(ug >> 1) * 8 + wv) * 512);
        const int row = lane >> 2, q4 = lane & 3;
        u64 v = *(const u64*)&stage[wv][row][q4 * 4];
        const int idx = (((ug & 1) * 2 + (q4 >> 1)) * 16 + row) * 2 + (q4 & 1);
        dst64[idx] = v;
    }
}

// Kept to match the harness-provided template symbol (unused).
__global__ void Sequence_85564338471528_kernel() {}

extern "C" void kernel_launch(void* const* d_in, const int* in_sizes, int n_in,
                              void* d_out, int out_size, void* d_ws, size_t ws_size,
                              hipStream_t stream)
{
    const float* x    = (const float*)d_in[0];
    const float* W1   = (const float*)d_in[2];
    const float* b1   = (const float*)d_in[3];
    const float* W2   = (const float*)d_in[4];
    const float* b2   = (const float*)d_in[5];
    const float* Wih1 = (const float*)d_in[6];
    const float* Whh1 = (const float*)d_in[7];
    const float* bih1 = (const float*)d_in[8];
    const float* bhh1 = (const float*)d_in[9];
    const float* Wih2 = (const float*)d_in[10];
    const float* Whh2 = (const float*)d_in[11];
    const float* bih2 = (const float*)d_in[12];
    const float* bhh2 = (const float*)d_in[13];
    const float* Wih3 = (const float*)d_in[14];
    const float* Whh3 = (const float*)d_in[15];
    const float* bih3 = (const float*)d_in[16];
    const float* bhh3 = (const float*)d_in[17];
    char* ws = (char*)d_ws;
    float* out = (float*)d_out;

    fill_sentinel<<<256, 256, 0, stream>>>(out);
    zero_state<<<396, 256, 0, stream>>>(ws);

    pack_w<<<4096, 256, 0, stream>>>(Whh1, (unsigned short*)(ws + OFF_WH1));
    pack_w<<<4096, 256, 0, stream>>>(Whh2, (unsigned short*)(ws + OFF_WH2));
    pack_w<<<4096, 256, 0, stream>>>(Whh3, (unsigned short*)(ws + OFF_WH3));
    pack_w<<<4096, 256, 0, stream>>>(Wih2, (unsigned short*)(ws + OFF_WI2));
    pack_w<<<4096, 256, 0, stream>>>(Wih3, (unsigned short*)(ws + OFF_WI3));
    prep_vec<<<8, 256, 0, stream>>>(Wih1, W1, b1, bih1, bhh1, bih2, bhh2, bih3, bhh3,
                                    (float*)(ws + OFF_V1), (float*)(ws + OFF_U1),
                                    (float*)(ws + OFF_B2), (float*)(ws + OFF_B3));
    prep_xt<<<256, 256, 0, stream>>>(x, (float*)(ws + OFF_XT));

    for (int w = 0; w < NSTEP; ++w)
        step_k<<<97, 512, 0, stream>>>(ws, W2, b2, out, w);
}